// Round 2
// baseline (359.841 us; speedup 1.0000x reference)
//
#include <hip/hip_runtime.h>

// sigma = 1e-4  ->  1/sigma = 1e4
#define INV_SIGMA 1.0e4f

typedef float v4f __attribute__((ext_vector_type(4)));
typedef int   v4i __attribute__((ext_vector_type(4)));

__device__ __forceinline__ float one_minus_prob(float d, int f) {
    // (f >= 0) ? 1 - sigmoid(-d/sigma) : 1   ==   (f >= 0) ? sigmoid(d/sigma) : 1
    float s = 1.0f / (1.0f + __expf(-d * INV_SIGMA));
    return (f >= 0) ? s : 1.0f;
}

__device__ __forceinline__ float quad_combine(float prod) {
    // combine the 4 quarter-products of a pixel (lanes 4k..4k+3)
    prod *= __shfl_xor(prod, 1, 4);
    prod *= __shfl_xor(prod, 2, 4);
    return prod;
}

// R4: force-hoisted loads via inline asm. R3 post-mortem: VGPR_Count=24 proved
// hipcc re-sank the "hoisted" loads into a ~2-round pipeline (sched_barrier(0)
// alone does not pin them; pressure-driven scheduling wins). Latency-bound at
// 3.0 TB/s with ~3 loads in flight per wave. Here one asm volatile block issues
// all 12 loads (4 rounds x {dists x4, p2f x4, zbuf x1}) back-to-back -- the
// compiler cannot reorder or shrink it, so 36 result VGPRs stay live and every
// wave keeps 12 loads outstanding (4x the in-flight bytes).
//
// Layout: each wave owns 256 consecutive chunks, round r = 64 chunks at byte
// stride 1024 (fits the 13-bit signed global_load imm offset -> one address
// pair per stream). Waits: before round r the r stores already issued sit
// newest in the vmcnt queue (in-order retire), so N = 12-3(r+1)+r = 9,7,5,3.
__global__ __launch_bounds__(256) void SelfShader_9921374454199_kernel(
    const float* __restrict__ zbuf,
    const float* __restrict__ dists,
    const int*   __restrict__ p2f,
    float*       __restrict__ out,
    long long nChunks)  // 4 * N*H*W
{
    const int t = threadIdx.x;
    const long long blockBase = (long long)blockIdx.x * 1024;  // chunks per block

    if (blockBase + 1024 <= nChunks) {
        const int wave = t >> 6;
        const int lane = t & 63;
        const long long c0 = blockBase + (long long)wave * 256 + lane;

        const float* dA = dists + (c0 << 2);          // 16 B per chunk
        const int*   fA = p2f   + (c0 << 2);
        const float* zA = zbuf  + ((c0 >> 2) << 4);   // 64 B per pixel, elem 0

        v4f d0, d1, d2, d3;
        v4i f0, f1, f2, f3;
        float z0, z1, z2, z3;

        asm volatile(
            "global_load_dwordx4 %0, %12, off\n\t"
            "global_load_dwordx4 %4, %13, off\n\t"
            "global_load_dword   %8, %14, off\n\t"
            "global_load_dwordx4 %1, %12, off offset:1024\n\t"
            "global_load_dwordx4 %5, %13, off offset:1024\n\t"
            "global_load_dword   %9, %14, off offset:1024\n\t"
            "global_load_dwordx4 %2, %12, off offset:2048\n\t"
            "global_load_dwordx4 %6, %13, off offset:2048\n\t"
            "global_load_dword   %10, %14, off offset:2048\n\t"
            "global_load_dwordx4 %3, %12, off offset:3072\n\t"
            "global_load_dwordx4 %7, %13, off offset:3072\n\t"
            "global_load_dword   %11, %14, off offset:3072\n\t"
            : "=&v"(d0), "=&v"(d1), "=&v"(d2), "=&v"(d3),
              "=&v"(f0), "=&v"(f1), "=&v"(f2), "=&v"(f3),
              "=&v"(z0), "=&v"(z1), "=&v"(z2), "=&v"(z3)
            : "v"(dA), "v"(fA), "v"(zA)
            : "memory");

        const bool isAlpha = (t & 3) == 3;

        // round 0: need oldest 3 loads done; 9 loads outstanding, 0 stores.
        asm volatile("s_waitcnt vmcnt(9)" ::: "memory");
        __builtin_amdgcn_sched_barrier(0);
        {
            float p = one_minus_prob(d0.x, f0.x) * one_minus_prob(d0.y, f0.y)
                    * one_minus_prob(d0.z, f0.z) * one_minus_prob(d0.w, f0.w);
            p = quad_combine(p);
            float v = isAlpha ? (1.0f - p) : z0;
            __builtin_nontemporal_store(v, out + c0);
        }
        // round 1: 6 loads outstanding + 1 store -> 7
        asm volatile("s_waitcnt vmcnt(7)" ::: "memory");
        __builtin_amdgcn_sched_barrier(0);
        {
            float p = one_minus_prob(d1.x, f1.x) * one_minus_prob(d1.y, f1.y)
                    * one_minus_prob(d1.z, f1.z) * one_minus_prob(d1.w, f1.w);
            p = quad_combine(p);
            float v = isAlpha ? (1.0f - p) : z1;
            __builtin_nontemporal_store(v, out + c0 + 64);
        }
        // round 2: 3 loads outstanding + 2 stores -> 5
        asm volatile("s_waitcnt vmcnt(5)" ::: "memory");
        __builtin_amdgcn_sched_barrier(0);
        {
            float p = one_minus_prob(d2.x, f2.x) * one_minus_prob(d2.y, f2.y)
                    * one_minus_prob(d2.z, f2.z) * one_minus_prob(d2.w, f2.w);
            p = quad_combine(p);
            float v = isAlpha ? (1.0f - p) : z2;
            __builtin_nontemporal_store(v, out + c0 + 128);
        }
        // round 3: 0 loads outstanding + 3 stores -> 3
        asm volatile("s_waitcnt vmcnt(3)" ::: "memory");
        __builtin_amdgcn_sched_barrier(0);
        {
            float p = one_minus_prob(d3.x, f3.x) * one_minus_prob(d3.y, f3.y)
                    * one_minus_prob(d3.z, f3.z) * one_minus_prob(d3.w, f3.w);
            p = quad_combine(p);
            float v = isAlpha ? (1.0f - p) : z3;
            __builtin_nontemporal_store(v, out + c0 + 192);
        }
    } else {
        // tail path (never taken for the bench shape: 8.39M chunks / 1024 exact).
        // nChunks is a multiple of 4, so each 4-lane quad is all-in or all-out
        // and the width-4 shuffles stay well-defined.
        const v4f* d4 = reinterpret_cast<const v4f*>(dists);
        const v4i* f4 = reinterpret_cast<const v4i*>(p2f);
        for (long long c = blockBase + t; c < nChunks; c += 256) {
            v4f   dd = d4[c];
            v4i   ff = f4[c];
            float zz = zbuf[(c >> 2) << 4];
            float prod = one_minus_prob(dd.x, ff.x) * one_minus_prob(dd.y, ff.y)
                       * one_minus_prob(dd.z, ff.z) * one_minus_prob(dd.w, ff.w);
            prod = quad_combine(prod);
            out[c] = ((t & 3) == 3) ? (1.0f - prod) : zz;
        }
    }
}

extern "C" void kernel_launch(void* const* d_in, const int* in_sizes, int n_in,
                              void* d_out, int out_size, void* d_ws, size_t ws_size,
                              hipStream_t stream) {
    const float* zbuf  = (const float*)d_in[0];
    const float* dists = (const float*)d_in[1];
    const int*   p2f   = (const int*)d_in[2];
    float*       out   = (float*)d_out;

    long long nChunks = (long long)in_sizes[0] / 4;  // 4 float4 chunks per pixel (K=16)
    const long long chunksPerBlock = 1024;           // 4 waves * 4 rounds * 64 lanes
    int grid = (int)((nChunks + chunksPerBlock - 1) / chunksPerBlock);
    SelfShader_9921374454199_kernel<<<grid, 256, 0, stream>>>(zbuf, dists, p2f, out, nChunks);
}

// Round 4
// 349.374 us; speedup vs baseline: 1.0300x; 1.0300x over previous
//
#include <hip/hip_runtime.h>

// sigma = 1e-4  ->  1/sigma = 1e4
#define INV_SIGMA 1.0e4f

typedef float v4f __attribute__((ext_vector_type(4)));
typedef int   v4i __attribute__((ext_vector_type(4)));

__device__ __forceinline__ float one_minus_prob(float d, int f) {
    // (f >= 0) ? 1 - sigmoid(-d/sigma) : 1   ==   (f >= 0) ? sigmoid(d/sigma) : 1
    // EXACT same expression as the 78us baseline -> bitwise-identical per element.
    float s = 1.0f / (1.0f + __expf(-d * INV_SIGMA));
    return (f >= 0) ? s : 1.0f;
}

// R5 (resubmit after infra failure): one thread = one pixel. R2 post-mortem:
// forced 12-deep asm load bursts REGRESSED (78->134us; also dropped nt +
// switched to flat addressing), and R0(24-deep)==R1(12-deep)==78us proved
// per-wave load depth was never the binding constraint. Remaining controllable
// cost at 78us: per-pixel serial tail (2 ds_swizzle cross-lane products
// ~120cy on the critical path), 4 redundant zbuf lane-loads, and 16 memory
// instructions per pixel.
//
// Here thread p owns pixel p: loads dists[16p..+15] and p2f[16p..+15] as
// 4+4 dwordx4 (64B/lane, fully line-coalesced across the wave), ONE zbuf
// dword, computes the K=16 product entirely in-register (zero DS ops), and
// stores one dwordx4 {z,z,z,alpha}. Per-pixel mem instrs 16->10, DS 2->0.
// Product tree replicates the old quad+shfl_xor tree exactly (IEEE mul is
// commutative bitwise), so absmax stays 0.0.
__global__ __launch_bounds__(256) void SelfShader_9921374454199_kernel(
    const float* __restrict__ zbuf,
    const float* __restrict__ dists,
    const int*   __restrict__ p2f,
    float*       __restrict__ out,
    long long nPixels)  // N*H*W
{
    const long long p = (long long)blockIdx.x * 256 + threadIdx.x;
    if (p >= nPixels) return;

    const v4f* d4 = reinterpret_cast<const v4f*>(dists) + (p << 2);
    const v4i* f4 = reinterpret_cast<const v4i*>(p2f)   + (p << 2);

    // 9 independent loads; results all live -> wave keeps ~9KB in flight.
    v4f d0 = __builtin_nontemporal_load(d4 + 0);
    v4f d1 = __builtin_nontemporal_load(d4 + 1);
    v4f d2 = __builtin_nontemporal_load(d4 + 2);
    v4f d3 = __builtin_nontemporal_load(d4 + 3);
    v4i f0 = __builtin_nontemporal_load(f4 + 0);
    v4i f1 = __builtin_nontemporal_load(f4 + 1);
    v4i f2 = __builtin_nontemporal_load(f4 + 2);
    v4i f3 = __builtin_nontemporal_load(f4 + 3);
    float z = __builtin_nontemporal_load(zbuf + (p << 4));

    // Quad products, left-assoc exactly like the baseline's per-thread chain.
    float c0 = ((one_minus_prob(d0.x, f0.x) * one_minus_prob(d0.y, f0.y))
               * one_minus_prob(d0.z, f0.z)) * one_minus_prob(d0.w, f0.w);
    float c1 = ((one_minus_prob(d1.x, f1.x) * one_minus_prob(d1.y, f1.y))
               * one_minus_prob(d1.z, f1.z)) * one_minus_prob(d1.w, f1.w);
    float c2 = ((one_minus_prob(d2.x, f2.x) * one_minus_prob(d2.y, f2.y))
               * one_minus_prob(d2.z, f2.z)) * one_minus_prob(d2.w, f2.w);
    float c3 = ((one_minus_prob(d3.x, f3.x) * one_minus_prob(d3.y, f3.y))
               * one_minus_prob(d3.z, f3.z)) * one_minus_prob(d3.w, f3.w);

    // Same pairing tree as the old shfl_xor reduction: (c0*c1)*(c2*c3).
    float P = (c0 * c1) * (c2 * c3);

    v4f o;
    o.x = z;
    o.y = z;
    o.z = z;
    o.w = 1.0f - P;
    __builtin_nontemporal_store(o, reinterpret_cast<v4f*>(out) + p);
}

extern "C" void kernel_launch(void* const* d_in, const int* in_sizes, int n_in,
                              void* d_out, int out_size, void* d_ws, size_t ws_size,
                              hipStream_t stream) {
    const float* zbuf  = (const float*)d_in[0];
    const float* dists = (const float*)d_in[1];
    const int*   p2f   = (const int*)d_in[2];
    float*       out   = (float*)d_out;

    long long nPixels = (long long)in_sizes[0] / 16;  // K=16 faces per pixel
    int grid = (int)((nPixels + 255) / 256);
    SelfShader_9921374454199_kernel<<<grid, 256, 0, stream>>>(zbuf, dists, p2f, out, nPixels);
}

// Round 5
// 331.101 us; speedup vs baseline: 1.0868x; 1.0552x over previous
//
#include <hip/hip_runtime.h>

// sigma = 1e-4  ->  1/sigma = 1e4
#define INV_SIGMA 1.0e4f
#define ROUNDS 8   // chunks per thread; 256 threads * 8 = 2048 chunks/block

typedef float v4f __attribute__((ext_vector_type(4)));
typedef int   v4i __attribute__((ext_vector_type(4)));

// R6: restore the proven chunk-transposed R0 structure (78us; R2 asm burst and
// R4 pixel-per-thread both regressed), change ONLY the math. Theory: at 78us
// no measured pipe is saturated (HBM 37%, LLC ~20%, VALU 23%); the unmeasured
// TRANS pipe is the floor. Old code: 4 exp + 4 f32-divisions per chunk, all
// quarter-rate on the shared per-SIMD trans unit (1 trans-op/chunk ~= 13.7us
// whole-kernel; observed 78us ~= 6 trans-ops/chunk). New: product of sigmoids
// == 1 / product(1+u), u = __expf(-d*1e4) (bitwise-identical exp inputs);
// quad-combine the (1+u) products via the same shfl_xor tree, ONE division per
// chunk on the alpha lane. Trans-ops/chunk ~8 -> ~5. Numerics: one correctly-
// rounded div replaces four -> |diff| vs reference ~1e-7 on alpha only.
__device__ __forceinline__ float term_1p(float d, int f) {
    // (f >= 0) ? 1 + exp(-d/sigma) : 1     [note: 1/(1+u) == sigmoid(d/sigma)]
    float u = __expf(-d * INV_SIGMA);
    return (f >= 0) ? (1.0f + u) : 1.0f;
}

__global__ __launch_bounds__(256) void SelfShader_9921374454199_kernel(
    const float* __restrict__ zbuf,
    const float* __restrict__ dists,
    const int*   __restrict__ p2f,
    float*       __restrict__ out,
    long long nChunks)  // 4 * N*H*W
{
    const int t = threadIdx.x;
    const long long cbase = (long long)blockIdx.x * (256 * ROUNDS) + t;

    const v4f* d4 = reinterpret_cast<const v4f*>(dists);
    const v4i* f4 = reinterpret_cast<const v4i*>(p2f);

    if (cbase + (ROUNDS - 1) * 256 < nChunks) {
        v4f   d[ROUNDS];
        v4i   f[ROUNDS];
        float z[ROUNDS];
#pragma unroll
        for (int r = 0; r < ROUNDS; ++r) {
            long long c = cbase + r * 256;
            d[r] = __builtin_nontemporal_load(d4 + c);
            f[r] = __builtin_nontemporal_load(f4 + c);
            // zbuf[pixel*16], pixel = c>>2; 4 lanes share an address (coalesces)
            z[r] = __builtin_nontemporal_load(zbuf + ((c >> 2) << 4));
        }
#pragma unroll
        for (int r = 0; r < ROUNDS; ++r) {
            long long c = cbase + r * 256;
            // product of (1+u) terms for this quarter-pixel
            float T = ((term_1p(d[r].x, f[r].x) * term_1p(d[r].y, f[r].y))
                      * term_1p(d[r].z, f[r].z)) * term_1p(d[r].w, f[r].w);
            // combine the 4 quarter-products of this pixel (lanes 4k..4k+3)
            T *= __shfl_xor(T, 1, 4);
            T *= __shfl_xor(T, 2, 4);
            // alpha = 1 - prod(sigmoid) = 1 - 1/prod(1+u): ONE division per chunk
            float v = ((t & 3) == 3) ? (1.0f - 1.0f / T) : z[r];
            __builtin_nontemporal_store(v, out + c);
        }
    } else {
        // tail path (never taken for the bench shape: 8.39M chunks / 2048 exact)
        for (int r = 0; r < ROUNDS; ++r) {
            long long c = cbase + r * 256;
            if (c >= nChunks) break;
            v4f   dd = d4[c];
            v4i   ff = f4[c];
            float zz = zbuf[(c >> 2) << 4];
            float T = ((term_1p(dd.x, ff.x) * term_1p(dd.y, ff.y))
                      * term_1p(dd.z, ff.z)) * term_1p(dd.w, ff.w);
            T *= __shfl_xor(T, 1, 4);
            T *= __shfl_xor(T, 2, 4);
            out[c] = ((t & 3) == 3) ? (1.0f - 1.0f / T) : zz;
        }
    }
}

extern "C" void kernel_launch(void* const* d_in, const int* in_sizes, int n_in,
                              void* d_out, int out_size, void* d_ws, size_t ws_size,
                              hipStream_t stream) {
    const float* zbuf  = (const float*)d_in[0];
    const float* dists = (const float*)d_in[1];
    const int*   p2f   = (const int*)d_in[2];
    float*       out   = (float*)d_out;

    long long nChunks = (long long)in_sizes[0] / 4;  // 4 float4 chunks per pixel (K=16)
    const long long chunksPerBlock = 256LL * ROUNDS;
    int grid = (int)((nChunks + chunksPerBlock - 1) / chunksPerBlock);
    SelfShader_9921374454199_kernel<<<grid, 256, 0, stream>>>(zbuf, dists, p2f, out, nChunks);
}